// Round 2
// baseline (261.564 us; speedup 1.0000x reference)
//
#include <hip/hip_runtime.h>
#include <math.h>

#define ROWS 8192
#define NCOL 2048
#define V 32
#define WPB 4                 // waves (rows) per block
#define THREADS (WPB * 64)

// static compare-exchange: ascending, both indices compile-time
__device__ __forceinline__ void ce(float& a, float& b) {
  const float lo = fminf(a, b);
  const float hi = fmaxf(a, b);
  a = lo; b = hi;
}

// med3(a,b,-inf)=min(a,b); med3(a,b,+inf)=max(a,b). One VALU op per
// cross-lane compare-exchange, direction baked into per-pass constant.
__device__ __forceinline__ float ce_dir(float a, float b, float cdir) {
  return __builtin_amdgcn_fmed3f(a, b, cdir);
}

// ---- cross-lane partner fetch x[lane ^ M] ----
// ds_swizzle BitMode for all masks <= 31: pattern is an IMMEDIATE -> zero
// VALU address overhead (this was the round-0 fat: __shfl_xor re-emits
// mbcnt/xor/shl address chains). Mask 63 uses ds_bpermute with an address
// VGPR computed ONCE at kernel entry. No DPP (round 1: VALU pipe is the
// binding resource; keep shuffles on the DS pipe).
template <int M>
__device__ __forceinline__ float lane_xor(float x, int a63) {
  if constexpr (M == 63) {
    return __builtin_bit_cast(
        float, __builtin_amdgcn_ds_bpermute(a63, __builtin_bit_cast(int, x)));
  } else {
    static_assert(M >= 1 && M <= 31, "swizzle mask");
    constexpr int pat = (M << 10) | 0x1F;  // BitMode: xor=M, or=0, and=0x1F
    return __builtin_bit_cast(
        float, __builtin_amdgcn_ds_swizzle(__builtin_bit_cast(int, x), pat));
  }
}

// cross-lane xor pass over both arrays, same element index, mask M.
// 16 independent DS ops in flight before the med3 batch.
template <int M>
__device__ __forceinline__ void xpass2(float (&a)[V], float (&b)[V],
                                       float cdir, int a63) {
#pragma unroll
  for (int c = 0; c < V; c += 8) {
    float oa[8], ob[8];
#pragma unroll
    for (int u = 0; u < 8; ++u) oa[u] = lane_xor<M>(a[c + u], a63);
#pragma unroll
    for (int u = 0; u < 8; ++u) ob[u] = lane_xor<M>(b[c + u], a63);
#pragma unroll
    for (int u = 0; u < 8; ++u) a[c + u] = ce_dir(a[c + u], oa[u], cdir);
#pragma unroll
    for (int u = 0; u < 8; ++u) b[c + u] = ce_dir(b[c + u], ob[u], cdir);
  }
}

// One bitonic merge stage for run length k = 64*KB (KB = 1..32):
// flip pass (partner lane^(2KB-1), elem v^31), xor passes KB/2..1,
// then the in-lane tail j = 16..1. Both arrays per pass for ILP.
template <int KB>
__device__ __forceinline__ void merge2(float (&a)[V], float (&b)[V],
                                       int lane, int a63) {
  {
    constexpr int LM = 2 * KB - 1;
    const float cdir = (lane & KB) ? INFINITY : -INFINITY;
#pragma unroll
    for (int q = 0; q < 4; ++q) {
      const int vA = 4 * q;
      float o[8];
#pragma unroll
      for (int u = 0; u < 4; ++u) {
        o[u]     = lane_xor<LM>(a[(vA + u) ^ 31], a63);
        o[u + 4] = lane_xor<LM>(a[vA + u], a63);
      }
#pragma unroll
      for (int u = 0; u < 4; ++u) {
        a[vA + u]        = ce_dir(a[vA + u],        o[u],     cdir);
        a[(vA + u) ^ 31] = ce_dir(a[(vA + u) ^ 31], o[u + 4], cdir);
      }
#pragma unroll
      for (int u = 0; u < 4; ++u) {
        o[u]     = lane_xor<LM>(b[(vA + u) ^ 31], a63);
        o[u + 4] = lane_xor<LM>(b[vA + u], a63);
      }
#pragma unroll
      for (int u = 0; u < 4; ++u) {
        b[vA + u]        = ce_dir(b[vA + u],        o[u],     cdir);
        b[(vA + u) ^ 31] = ce_dir(b[(vA + u) ^ 31], o[u + 4], cdir);
      }
    }
  }
  if constexpr (KB >= 32) {
    const float cd = (lane & 16) ? INFINITY : -INFINITY;
    xpass2<16>(a, b, cd, a63);
  }
  if constexpr (KB >= 16) {
    const float cd = (lane & 8) ? INFINITY : -INFINITY;
    xpass2<8>(a, b, cd, a63);
  }
  if constexpr (KB >= 8) {
    const float cd = (lane & 4) ? INFINITY : -INFINITY;
    xpass2<4>(a, b, cd, a63);
  }
  if constexpr (KB >= 4) {
    const float cd = (lane & 2) ? INFINITY : -INFINITY;
    xpass2<2>(a, b, cd, a63);
  }
  if constexpr (KB >= 2) {
    const float cd = (lane & 1) ? INFINITY : -INFINITY;
    xpass2<1>(a, b, cd, a63);
  }
  // in-lane xor passes j = 16..1: static indices AND static direction
#pragma unroll
  for (int j = 16; j >= 1; j >>= 1) {
#pragma unroll
    for (int v = 0; v < V; ++v) {
      if ((v & j) == 0) {
        ce(a[v], a[v | j]);
        ce(b[v], b[v | j]);
      }
    }
  }
}

// One wave per row; lane holds elements e = lane*32 + v of both arrays in
// registers. Normalized bitonic sort (all compares ascending).
__global__ __launch_bounds__(THREADS, 4) void sort_mse_kernel(
    const float* __restrict__ pred, const float* __restrict__ targ,
    float* __restrict__ out) {
  const int lane = threadIdx.x & 63;
  const int wave = threadIdx.x >> 6;
  const int row = blockIdx.x * WPB + wave;
  const size_t base = (size_t)row * NCOL + (size_t)lane * V;
  const int a63 = ((lane ^ 63) << 2);  // bpermute byte addr, computed once

  float rp[V], rt[V];
  const float4* p4 = (const float4*)(pred + base);
  const float4* t4 = (const float4*)(targ + base);
#pragma unroll
  for (int q = 0; q < V / 4; ++q) {
    const float4 a = p4[q];
    rp[4 * q + 0] = a.x; rp[4 * q + 1] = a.y;
    rp[4 * q + 2] = a.z; rp[4 * q + 3] = a.w;
    const float4 b = t4[q];
    rt[4 * q + 0] = b.x; rt[4 * q + 1] = b.y;
    rt[4 * q + 2] = b.z; rt[4 * q + 3] = b.w;
  }

  // ---- Phase 1: stages k = 2..32, fully in-lane, fully static ----
#pragma unroll
  for (int k = 2; k <= V; k <<= 1) {
#pragma unroll
    for (int v = 0; v < V; ++v) {
      if ((v & (k >> 1)) == 0) {
        ce(rp[v], rp[v ^ (k - 1)]);
        ce(rt[v], rt[v ^ (k - 1)]);
      }
    }
#pragma unroll
    for (int j = k >> 2; j >= 1; j >>= 1) {
#pragma unroll
      for (int v = 0; v < V; ++v) {
        if ((v & j) == 0) {
          ce(rp[v], rp[v | j]);
          ce(rt[v], rt[v | j]);
        }
      }
    }
  }

  // ---- Phase 2: stages k = 64..2048 (KB = k/64 = 1..32) ----
  merge2<1>(rp, rt, lane, a63);
  merge2<2>(rp, rt, lane, a63);
  merge2<4>(rp, rt, lane, a63);
  merge2<8>(rp, rt, lane, a63);
  merge2<16>(rp, rt, lane, a63);
  merge2<32>(rp, rt, lane, a63);

  // ranks are matched at identical (lane, v) after both sorts
  float acc = 0.f;
#pragma unroll
  for (int v = 0; v < V; ++v) {
    const float d = rp[v] - rt[v];
    acc = fmaf(d, d, acc);
  }
#pragma unroll
  for (int off = 32; off > 0; off >>= 1) acc += __shfl_down(acc, off, 64);
  if (lane == 0) {
    unsafeAtomicAdd(out, acc * (1.0f / ((float)ROWS * (float)NCOL)));
  }
}

extern "C" void kernel_launch(void* const* d_in, const int* in_sizes, int n_in,
                              void* d_out, int out_size, void* d_ws, size_t ws_size,
                              hipStream_t stream) {
  const float* pred = (const float*)d_in[0];
  const float* targ = (const float*)d_in[1];
  float* out = (float*)d_out;

  hipMemsetAsync(out, 0, sizeof(float), stream);  // d_out is re-poisoned 0xAA
  sort_mse_kernel<<<ROWS / WPB, THREADS, 0, stream>>>(pred, targ, out);
}